// Round 1
// baseline (326.088 us; speedup 1.0000x reference)
//
#include <hip/hip_runtime.h>
#include <hip/hip_bf16.h>
#include <stdint.h>

typedef float  f32x4  __attribute__((ext_vector_type(4)));
typedef float  f32x16 __attribute__((ext_vector_type(16)));
typedef unsigned int   u32x4 __attribute__((ext_vector_type(4)));
typedef unsigned short u16x4 __attribute__((ext_vector_type(4)));
typedef int    i32x4  __attribute__((ext_vector_type(4)));

__device__ inline unsigned short f2bf(float f) {
  unsigned int u = __builtin_bit_cast(unsigned int, f);
  u += 0x7fffu + ((u >> 16) & 1u);   // round-to-nearest-even
  return (unsigned short)(u >> 16);
}

__device__ inline void mfma32x32x16bf16(f32x16& acc, u32x4 a, u32x4 b) {
  asm volatile("v_mfma_f32_32x32x16_bf16 %0, %1, %2, %0"
               : "+v"(acc)
               : "v"(a), "v"(b));
}

__device__ inline void mfma16x16x32bf16(f32x4& acc, u32x4 a, u32x4 b) {
  asm volatile("v_mfma_f32_16x16x32_bf16 %0, %1, %2, %0"
               : "+v"(acc)
               : "v"(a), "v"(b));
}

__device__ inline void gload16(const unsigned short* src, char* ldsdst) {
  __builtin_amdgcn_global_load_lds(
      (const __attribute__((address_space(1))) void*)src,
      (__attribute__((address_space(3))) void*)ldsdst, 16, 0, 0);
}

// ======================================================================
// Fragment-ordered tiles for 32x32x16 MFMA (verified R3-R7).
// Tile (256 rows x 64 k) = 2048 chunks of 16B. Chunk c = s*512 + f*64 + lane
//   (s = k>>4, f = row>>5, lane = (row&31) + 32*((k>>3)&1)); 8 bf16/chunk.
// Each kh half (s pair) = contiguous 16 KB = one BK=32 subtile.
// ======================================================================

// prep_x: x fp32 [M][K] -> xb fragment-ordered bf16
__global__ __launch_bounds__(256) void prep_x(const float* __restrict__ x,
                                              unsigned short* __restrict__ xb,
                                              int K, int KT) {
  const int rb = blockIdx.x / KT;
  const int kt = blockIdx.x % KT;
  __shared__ unsigned short t[256 * 64];
  const int tid = threadIdx.x;
  const int klane = tid & 15;        // *4 floats along k
  const int rbase = tid >> 4;        // 0..15
  const float* src = x + (size_t)(rb * 256) * K + kt * 64;
  const int gw = klane >> 1, hw = klane & 1;   // 8-elem group, half
  for (int it = 0; it < 16; ++it) {
    int row = it * 16 + rbase;
    f32x4 v = *(const f32x4*)(src + (size_t)row * K + klane * 4);
    u16x4 h;
    h[0] = f2bf(v[0]); h[1] = f2bf(v[1]); h[2] = f2bf(v[2]); h[3] = f2bf(v[3]);
    *(u16x4*)&t[row * 64 + ((gw ^ (row & 7)) << 3) + hw * 4] = h;   // XOR-swizzled
  }
  __syncthreads();
  unsigned short* dst = xb + ((size_t)rb * KT + kt) * 16384;
  for (int j = 0; j < 8; ++j) {
    int c = j * 256 + tid;            // output-linear 16B chunk index
    int l = c & 63, f = (c >> 6) & 7, s = c >> 9;
    int row = f * 32 + (l & 31);
    int g   = (s * 2 + (l >> 5)) ^ (row & 7);
    u32x4 v = *(const u32x4*)&t[row * 64 + (g << 3)];
    *(u32x4*)(dst + (size_t)c * 8) = v;
  }
}

// prep_w: wq int32 [N][K], zp -> wb = bf16(w - zp) fragment-ordered
__global__ __launch_bounds__(256) void prep_w(const int* __restrict__ wq,
                                              const int* __restrict__ zp,
                                              unsigned short* __restrict__ wb,
                                              int K, int KT) {
  const int cb = blockIdx.x / KT;
  const int kt = blockIdx.x % KT;
  __shared__ unsigned short t[256 * 64];
  const int tid = threadIdx.x;
  const int klane = tid & 15;
  const int rbase = tid >> 4;
  const int* src = wq + (size_t)(cb * 256) * K + kt * 64;
  const int gw = klane >> 1, hw = klane & 1;
  for (int it = 0; it < 16; ++it) {
    int row = it * 16 + rbase;
    i32x4 v = *(const i32x4*)(src + (size_t)row * K + klane * 4);
    int z = zp[cb * 256 + row];
    u16x4 h;
    h[0] = f2bf((float)(v[0] - z)); h[1] = f2bf((float)(v[1] - z));
    h[2] = f2bf((float)(v[2] - z)); h[3] = f2bf((float)(v[3] - z));
    *(u16x4*)&t[row * 64 + ((gw ^ (row & 7)) << 3) + hw * 4] = h;
  }
  __syncthreads();
  unsigned short* dst = wb + ((size_t)cb * KT + kt) * 16384;
  for (int j = 0; j < 8; ++j) {
    int c = j * 256 + tid;
    int l = c & 63, f = (c >> 6) & 7, s = c >> 9;
    int row = f * 32 + (l & 31);
    int g   = (s * 2 + (l >> 5)) ^ (row & 7);
    u32x4 v = *(const u32x4*)&t[row * 64 + (g << 3)];
    *(u32x4*)(dst + (size_t)c * 8) = v;
  }
}

// ======================================================================
// 256x256 GEMM, 32x32x16 MFMA.
// R8 change: B operands bypass LDS entirely. Fragment-ordered wb means a
// wave's B-frag (s,n) is a contiguous 1 KB global read (base + lane*16),
// fully coalesced; the 2 waves sharing wc read identical addresses (L1
// broadcast). B-frags are loaded global->VGPR double-buffered one subtile
// ahead (static bA/bB rotation, no runtime indexing). A keeps the proven
// global_load_lds 4-slot ring (16 KB slots, depth-3).
// LDS pipe per subtile per CU drops 96KB rd + 32KB wr (~1400cyc) ->
// 64KB rd + 16KB wr (~900cyc), below the 1033cyc matrix-pipe floor.
//
// vmcnt ledger (per-thread VMEM queue, oldest->newest), per-iter issue
// order is [Bdir(u+1) x4, stageA(u+3) x2]:
//   steady state before wait at iter u:
//     stageA(u+1)2, Bdir(u)4, stageA(u+2)2, Bdir(u+1)4, stageA(u+3)2 = 14
//   need Bdir(u) (and stageA(u), ancient) done -> drain 6 -> vmcnt(8).
//   tails: u=KT-3 -> vmcnt(6); u=KT-2 -> vmcnt(4); u=KT-1 -> vmcnt(0).
// ======================================================================
__global__ __launch_bounds__(512, 2) void gemm_ring(
    const unsigned short* __restrict__ xb, const unsigned short* __restrict__ wb,
    const float* __restrict__ scale, const float* __restrict__ bias,
    float* __restrict__ out, int N, int KT) {   // KT = K/32 subtiles

  __shared__ unsigned short lds[32768];   // 64 KiB = 4 slots x 16 KB (A only)

  const int NB = N >> 8;
  // T1: XCD-aware swizzle (nwg % 8 == 0 guaranteed by launcher)
  const int nwg = gridDim.x;
  const int wg  = (blockIdx.x & 7) * (nwg >> 3) + (blockIdx.x >> 3);
  const int rb = wg / NB;
  const int cb = wg % NB;

  const int tid  = threadIdx.x;
  const int lane = tid & 63;
  const int wave = tid >> 6;
  const int wr = wave >> 2;        // 0..1  (M)
  const int wc = wave & 3;         // 0..3  (N)
  const int wr4 = wr * 4, wc2 = wc * 2;
  const int lane16 = lane * 16;

  // subtile u of A: xtb + u*8192 shorts (16 KB); same for B
  const unsigned short* xtb = xb + (size_t)rb * (KT >> 1) * 16384;
  const unsigned short* wtb = wb + (size_t)cb * (KT >> 1) * 16384;

  f32x16 acc[4][2] = {};
  u32x4 bA[2][2], bB[2][2];        // B-frag double buffer (static rotation)

  auto STAGE = [&](int u) {
    const int slot = (u & 3) << 14;                 // 16 KB slots (A only)
    const unsigned short* as = xtb + (size_t)u * 8192;
    char* da = (char*)lds + slot + wave * 2048;           // wave-uniform
    gload16(as + wave * 1024 + lane * 8, da);
    gload16(as + wave * 1024 + 512 + lane * 8, da + 1024);
  };

  auto LDA = [&](int slotb, int s, int m) -> u32x4 {
    return *(const u32x4*)((const char*)lds + slotb + s * 8192 +
                           (wr4 + m) * 1024 + lane16);
  };

#define BODY(U, CUR, NXT, VM, DOB, DOS)                                        \
  {                                                                            \
    const int u_ = (U);                                                        \
    const int sb = (u_ & 3) << 14;                                             \
    __builtin_amdgcn_s_barrier();  /* slot (u_+3)&3 == (u_-1)&3 now free */    \
    if (DOB) {                                                                 \
      const unsigned short* bsrc = wtb + (size_t)(u_ + 1) * 8192 + lane * 8;   \
      _Pragma("unroll")                                                        \
      for (int s = 0; s < 2; ++s)                                              \
        _Pragma("unroll")                                                      \
        for (int n = 0; n < 2; ++n)                                            \
          NXT[s][n] = *(const u32x4*)(bsrc + s * 4096 + (wc2 + n) * 512);      \
    }                                                                          \
    if (DOS) STAGE(u_ + 3);                                                    \
    asm volatile("s_waitcnt vmcnt(" #VM ")" ::: "memory");                     \
    __builtin_amdgcn_s_setprio(1);                                             \
    _Pragma("unroll")                                                          \
    for (int s = 0; s < 2; ++s)                                                \
      _Pragma("unroll")                                                        \
      for (int m = 0; m < 4; ++m) {                                            \
        u32x4 a = LDA(sb, s, m);                                               \
        mfma32x32x16bf16(acc[m][0], a, CUR[s][0]);                             \
        mfma32x32x16bf16(acc[m][1], a, CUR[s][1]);                             \
      }                                                                        \
    __builtin_amdgcn_s_setprio(0);                                             \
  }

  // -------- prologue: B(0) direct + A depth-3 --------
  {
    const unsigned short* bsrc = wtb + lane * 8;
#pragma unroll
    for (int s = 0; s < 2; ++s)
#pragma unroll
      for (int n = 0; n < 2; ++n)
        bA[s][n] = *(const u32x4*)(bsrc + s * 4096 + (wc2 + n) * 512);
  }
  STAGE(0); STAGE(1); STAGE(2);

  // KT is even and >= 8 (launcher guarantees). Pair loop exits at u = KT-4.
  int u = 0;
  for (; u + 4 < KT; u += 2) {
    BODY(u,     bA, bB, 8, true, true);
    BODY(u + 1, bB, bA, 8, true, true);
  }
  BODY(u, bA, bB, 8, true,  true);  ++u;   // u = KT-4 (stages KT-1)
  BODY(u, bB, bA, 6, true,  false); ++u;   // u = KT-3
  BODY(u, bA, bB, 4, true,  false); ++u;   // u = KT-2
  BODY(u, bB, bA, 0, false, false);        // u = KT-1
#undef BODY

  // -------- epilogue: C/D layout col=lane&31, row=(reg&3)+8*(reg>>2)+4*(lane>>5)
  const int m0 = rb * 256 + wr * 128;
  const int n0 = cb * 256 + wc * 64;
  const int l31 = lane & 31, lhi = lane >> 5;
#pragma unroll
  for (int n = 0; n < 2; ++n) {
    const int col = n0 + n * 32 + l31;
    const float sc = scale[col];
    const float bi = bias[col];
#pragma unroll
    for (int m = 0; m < 4; ++m) {
      f32x16 v = acc[m][n];
      const int rowb = m0 + m * 32 + 4 * lhi;
#pragma unroll
      for (int q = 0; q < 4; ++q)
#pragma unroll
        for (int r = 0; r < 4; ++r)
          out[(size_t)(rowb + q * 8 + r) * N + col] = v[q * 4 + r] * sc + bi;
    }
  }
}

// ======================================================================
// Fallback (no workspace): 128x128 tile, in-loop dequant, 16x16x32
// ======================================================================
__global__ __launch_bounds__(256) void gemm_fallback(
    const float* __restrict__ x, const int* __restrict__ wq, const int* __restrict__ zp,
    const float* __restrict__ scale, const float* __restrict__ bias,
    float* __restrict__ out, int M, int N, int K) {

  __shared__ unsigned short Alds[128 * 32];
  __shared__ unsigned short Blds[128 * 32];

  const int tid = threadIdx.x;
  const int ntile = N / 128;
  const int m0 = (blockIdx.x / ntile) * 128, n0 = (blockIdx.x % ntile) * 128;
  const int lane = tid & 63;
  const int wave = tid >> 6;
  const int wr = wave >> 1, wc = wave & 1;
  const int lr = lane & 15, lhi = lane >> 4;
  f32x4 acc[4][4] = {};
  const int ar = tid >> 3, ac4 = tid & 7;

  for (int k0 = 0; k0 < K; k0 += 32) {
#pragma unroll
    for (int p = 0; p < 4; ++p) {
      int r = p * 32 + ar;
      i32x4 w = *(const i32x4*)(wq + (size_t)(n0 + r) * K + k0 + ac4 * 4);
      int z = zp[n0 + r];
      u16x4 h;
      h[0] = f2bf((float)(w[0] - z)); h[1] = f2bf((float)(w[1] - z));
      h[2] = f2bf((float)(w[2] - z)); h[3] = f2bf((float)(w[3] - z));
      *(u16x4*)&Blds[r * 32 + ac4 * 4] = h;
    }
#pragma unroll
    for (int p = 0; p < 4; ++p) {
      int r = p * 32 + ar;
      f32x4 v = *(const f32x4*)(x + (size_t)(m0 + r) * K + k0 + ac4 * 4);
      u16x4 h;
      h[0] = f2bf(v[0]); h[1] = f2bf(v[1]); h[2] = f2bf(v[2]); h[3] = f2bf(v[3]);
      *(u16x4*)&Alds[r * 32 + ac4 * 4] = h;
    }
    __syncthreads();
    u32x4 af[4], bf[4];
#pragma unroll
    for (int i = 0; i < 4; ++i) {
      af[i] = *(const u32x4*)&Alds[(wr * 64 + i * 16 + lr) * 32 + lhi * 8];
      bf[i] = *(const u32x4*)&Blds[(wc * 64 + i * 16 + lr) * 32 + lhi * 8];
    }
#pragma unroll
    for (int i = 0; i < 4; ++i)
#pragma unroll
      for (int j = 0; j < 4; ++j)
        mfma16x16x32bf16(acc[i][j], af[i], bf[j]);
    __syncthreads();
  }
  const int crow0 = m0 + wr * 64;
  const int ccol0 = n0 + wc * 64 + lr;
#pragma unroll
  for (int j = 0; j < 4; ++j) {
    int col = ccol0 + j * 16;
    float sc = scale[col], bi = bias[col];
#pragma unroll
    for (int i = 0; i < 4; ++i) {
      int row = crow0 + i * 16 + lhi * 4;
      f32x4 v = acc[i][j];
#pragma unroll
      for (int r = 0; r < 4; ++r)
        out[(size_t)(row + r) * N + col] = v[r] * sc + bi;
    }
  }
}

extern "C" void kernel_launch(void* const* d_in, const int* in_sizes, int n_in,
                              void* d_out, int out_size, void* d_ws, size_t ws_size,
                              hipStream_t stream) {
  const float* x     = (const float*)d_in[0];
  const int*   wq    = (const int*)d_in[1];
  const float* scale = (const float*)d_in[2];
  const int*   zp    = (const int*)d_in[3];
  const float* bias  = (const float*)d_in[4];
  float* out = (float*)d_out;

  const int DOUT = in_sizes[4];             // 4096
  const int DIN  = in_sizes[1] / DOUT;      // 4096
  const int M    = in_sizes[0] / DIN;       // 8192

  const size_t needX = (size_t)M * DIN * 2;
  const size_t needW = (size_t)DOUT * DIN * 2;

  const int nwg  = (M / 256) * (DOUT / 256);
  const int KT64 = DIN / 64;
  const int KT32 = DIN / 32;
  const bool shapes_ok = (M % 256 == 0) && (DOUT % 256 == 0) && (DIN % 64 == 0) &&
                         (nwg % 8 == 0) && (KT32 >= 8) && (KT32 % 2 == 0);

  if (shapes_ok && ws_size >= needX + needW) {
    unsigned short* xb = (unsigned short*)d_ws;
    unsigned short* wb = (unsigned short*)((char*)d_ws + needX);
    prep_x<<<(M / 256) * KT64, 256, 0, stream>>>(x, xb, DIN, KT64);
    prep_w<<<(DOUT / 256) * KT64, 256, 0, stream>>>(wq, zp, wb, DIN, KT64);
    gemm_ring<<<nwg, 512, 0, stream>>>(xb, wb, scale, bias, out, DOUT, KT32);
  } else {
    dim3 grid((M / 128) * (DOUT / 128));
    gemm_fallback<<<grid, 256, 0, stream>>>(x, wq, zp, scale, bias, out, M, DOUT, DIN);
  }
}

// Round 2
// 295.217 us; speedup vs baseline: 1.1046x; 1.1046x over previous
//
#include <hip/hip_runtime.h>
#include <hip/hip_bf16.h>
#include <stdint.h>

typedef float  f32x4  __attribute__((ext_vector_type(4)));
typedef float  f32x16 __attribute__((ext_vector_type(16)));
typedef unsigned int   u32x4 __attribute__((ext_vector_type(4)));
typedef unsigned short u16x4 __attribute__((ext_vector_type(4)));
typedef int    i32x4  __attribute__((ext_vector_type(4)));

__device__ inline unsigned short f2bf(float f) {
  unsigned int u = __builtin_bit_cast(unsigned int, f);
  u += 0x7fffu + ((u >> 16) & 1u);   // round-to-nearest-even
  return (unsigned short)(u >> 16);
}

__device__ inline void mfma32x32x16bf16(f32x16& acc, u32x4 a, u32x4 b) {
  asm volatile("v_mfma_f32_32x32x16_bf16 %0, %1, %2, %0"
               : "+v"(acc)
               : "v"(a), "v"(b));
}

__device__ inline void mfma16x16x32bf16(f32x4& acc, u32x4 a, u32x4 b) {
  asm volatile("v_mfma_f32_16x16x32_bf16 %0, %1, %2, %0"
               : "+v"(acc)
               : "v"(a), "v"(b));
}

__device__ inline void gload16(const unsigned short* src, char* ldsdst) {
  __builtin_amdgcn_global_load_lds(
      (const __attribute__((address_space(1))) void*)src,
      (__attribute__((address_space(3))) void*)ldsdst, 16, 0, 0);
}

// ======================================================================
// Fragment-ordered tiles for 32x32x16 MFMA (verified R3-R7).
// Tile (256 rows x 64 k) = 2048 chunks of 16B. Chunk c = s*512 + f*64 + lane
//   (s = k>>4, f = row>>5, lane = (row&31) + 32*((k>>3)&1)); 8 bf16/chunk.
// Each kh half (s pair) = contiguous 16 KB = one BK=32 subtile.
// ======================================================================

// prep_x: x fp32 [M][K] -> xb fragment-ordered bf16
__global__ __launch_bounds__(256) void prep_x(const float* __restrict__ x,
                                              unsigned short* __restrict__ xb,
                                              int K, int KT) {
  const int rb = blockIdx.x / KT;
  const int kt = blockIdx.x % KT;
  __shared__ unsigned short t[256 * 64];
  const int tid = threadIdx.x;
  const int klane = tid & 15;        // *4 floats along k
  const int rbase = tid >> 4;        // 0..15
  const float* src = x + (size_t)(rb * 256) * K + kt * 64;
  const int gw = klane >> 1, hw = klane & 1;   // 8-elem group, half
  for (int it = 0; it < 16; ++it) {
    int row = it * 16 + rbase;
    f32x4 v = *(const f32x4*)(src + (size_t)row * K + klane * 4);
    u16x4 h;
    h[0] = f2bf(v[0]); h[1] = f2bf(v[1]); h[2] = f2bf(v[2]); h[3] = f2bf(v[3]);
    *(u16x4*)&t[row * 64 + ((gw ^ (row & 7)) << 3) + hw * 4] = h;   // XOR-swizzled
  }
  __syncthreads();
  unsigned short* dst = xb + ((size_t)rb * KT + kt) * 16384;
  for (int j = 0; j < 8; ++j) {
    int c = j * 256 + tid;            // output-linear 16B chunk index
    int l = c & 63, f = (c >> 6) & 7, s = c >> 9;
    int row = f * 32 + (l & 31);
    int g   = (s * 2 + (l >> 5)) ^ (row & 7);
    u32x4 v = *(const u32x4*)&t[row * 64 + (g << 3)];
    *(u32x4*)(dst + (size_t)c * 8) = v;
  }
}

// prep_w: wq int32 [N][K], zp -> wb = bf16(w - zp) fragment-ordered
__global__ __launch_bounds__(256) void prep_w(const int* __restrict__ wq,
                                              const int* __restrict__ zp,
                                              unsigned short* __restrict__ wb,
                                              int K, int KT) {
  const int cb = blockIdx.x / KT;
  const int kt = blockIdx.x % KT;
  __shared__ unsigned short t[256 * 64];
  const int tid = threadIdx.x;
  const int klane = tid & 15;
  const int rbase = tid >> 4;
  const int* src = wq + (size_t)(cb * 256) * K + kt * 64;
  const int gw = klane >> 1, hw = klane & 1;
  for (int it = 0; it < 16; ++it) {
    int row = it * 16 + rbase;
    i32x4 v = *(const i32x4*)(src + (size_t)row * K + klane * 4);
    int z = zp[cb * 256 + row];
    u16x4 h;
    h[0] = f2bf((float)(v[0] - z)); h[1] = f2bf((float)(v[1] - z));
    h[2] = f2bf((float)(v[2] - z)); h[3] = f2bf((float)(v[3] - z));
    *(u16x4*)&t[row * 64 + ((gw ^ (row & 7)) << 3) + hw * 4] = h;
  }
  __syncthreads();
  unsigned short* dst = wb + ((size_t)cb * KT + kt) * 16384;
  for (int j = 0; j < 8; ++j) {
    int c = j * 256 + tid;
    int l = c & 63, f = (c >> 6) & 7, s = c >> 9;
    int row = f * 32 + (l & 31);
    int g   = (s * 2 + (l >> 5)) ^ (row & 7);
    u32x4 v = *(const u32x4*)&t[row * 64 + (g << 3)];
    *(u32x4*)(dst + (size_t)c * 8) = v;
  }
}

// ======================================================================
// 256x256 GEMM, 32x32x16 MFMA, 4-slot LDS ring, BK=32 subtiles.
// 512 thr = 8 waves (2M x 4N), per-wave 128x64 = 4x2 frags.
// Slot (32 KB) = A subtile 16 KB + B subtile 16 KB. Depth-3 prefetch.
//
// R9 change (vs R7): B-fragments are register-prefetched ONE SUBTILE
// AHEAD (ping-pong bA/bB, static rotation). At barrier-exit the MFMA
// cluster's B operands are already in VGPRs, so the matrix pipe is
// gated only by the first LDA ds_read instead of 4 LDB + 1 LDA serial
// ramp. Costs +16 VGPR (combined ~244/wave, still 2 waves/SIMD).
//
// vmcnt ledger (4 gloads per STAGE), per-iter order:
//   [wait vmcnt(VM); barrier; LDB-prefetch(u+1); STAGE(u+3); MFMA(u)]
// The wait must cover stage(u+1) (its B is prefetched this iter):
//   outstanding before wait at iter u: [stage(u+1)4, stage(u+2)4] = 8
//   -> vmcnt(4) drains stage(u+1). Issued at iter u-2: 2 full
//   iterations of slack (>> 900cyc HBM latency). Never drained to 0
//   mid-loop. Tails: KT-2 and KT-1 use vmcnt(0).
// WAR safety: STAGE(u+3) overwrites slot (u-1)&3 AFTER the barrier, by
// which every wave has consumed its slot-(u-1) ds_reads (lgkm-waited
// before their MFMA uses). LDB-prefetch of slot (u+1) is overwritten
// only by STAGE(u+5) at iter u+2, long after consumption at iter u+1.
// ======================================================================
__global__ __launch_bounds__(512, 2) void gemm_ring(
    const unsigned short* __restrict__ xb, const unsigned short* __restrict__ wb,
    const float* __restrict__ scale, const float* __restrict__ bias,
    float* __restrict__ out, int N, int KT) {   // KT = K/32 subtiles

  __shared__ unsigned short lds[65536];   // 128 KiB = 4 slots x 32 KB

  const int NB = N >> 8;
  // T1: XCD-aware swizzle (nwg % 8 == 0 guaranteed by launcher)
  const int nwg = gridDim.x;
  const int wg  = (blockIdx.x & 7) * (nwg >> 3) + (blockIdx.x >> 3);
  const int rb = wg / NB;
  const int cb = wg % NB;

  const int tid  = threadIdx.x;
  const int lane = tid & 63;
  const int wave = tid >> 6;
  const int wr = wave >> 2;        // 0..1  (M)
  const int wc = wave & 3;         // 0..3  (N)
  const int wr4 = wr * 4, wc2 = wc * 2;
  const int lane16 = lane * 16;

  // subtile u of A: xtb + u*8192 shorts (16 KB); same for B
  const unsigned short* xtb = xb + (size_t)rb * (KT >> 1) * 16384;
  const unsigned short* wtb = wb + (size_t)cb * (KT >> 1) * 16384;

  f32x16 acc[4][2] = {};
  u32x4 bA[2][2], bB[2][2];        // B-frag ping-pong (static rotation)

  auto STAGE = [&](int u) {
    const int slot = (u & 3) << 15;                 // 32 KB slots
    const unsigned short* as = xtb + (size_t)u * 8192;
    const unsigned short* bs = wtb + (size_t)u * 8192;
    char* da = (char*)lds + slot + wave * 2048;           // wave-uniform
    char* db = (char*)lds + slot + 16384 + wave * 2048;
    gload16(as + wave * 1024 + lane * 8, da);
    gload16(as + wave * 1024 + 512 + lane * 8, da + 1024);
    gload16(bs + wave * 1024 + lane * 8, db);
    gload16(bs + wave * 1024 + 512 + lane * 8, db + 1024);
  };

  auto LDA = [&](int slotb, int s, int m) -> u32x4 {
    return *(const u32x4*)((const char*)lds + slotb + s * 8192 +
                           (wr4 + m) * 1024 + lane16);
  };
  auto LDB = [&](int slotb, int s, int n) -> u32x4 {
    return *(const u32x4*)((const char*)lds + slotb + 16384 + s * 8192 +
                           (wc2 + n) * 1024 + lane16);
  };

#define BODY(U, CUR, NXT, VM, DOB, DOS)                                        \
  {                                                                            \
    const int u_ = (U);                                                        \
    const int sb  = (u_ & 3) << 15;                                            \
    const int sbn = ((u_ + 1) & 3) << 15;                                      \
    asm volatile("s_waitcnt vmcnt(" #VM ")" ::: "memory");                     \
    __builtin_amdgcn_s_barrier();                                              \
    if (DOB) {                                                                 \
      _Pragma("unroll")                                                        \
      for (int s = 0; s < 2; ++s)                                              \
        _Pragma("unroll")                                                      \
        for (int n = 0; n < 2; ++n) NXT[s][n] = LDB(sbn, s, n);                \
    }                                                                          \
    if (DOS) STAGE(u_ + 3);                                                    \
    __builtin_amdgcn_s_setprio(1);                                             \
    _Pragma("unroll")                                                          \
    for (int s = 0; s < 2; ++s)                                                \
      _Pragma("unroll")                                                        \
      for (int m = 0; m < 4; ++m) {                                            \
        u32x4 a = LDA(sb, s, m);                                               \
        mfma32x32x16bf16(acc[m][0], a, CUR[s][0]);                             \
        mfma32x32x16bf16(acc[m][1], a, CUR[s][1]);                             \
      }                                                                        \
    __builtin_amdgcn_s_setprio(0);                                             \
  }

  // -------- prologue: depth-3 stage, then prefetch B(0) into bA --------
  STAGE(0); STAGE(1); STAGE(2);
  asm volatile("s_waitcnt vmcnt(8)" ::: "memory");   // stage(0) complete
  __builtin_amdgcn_s_barrier();
#pragma unroll
  for (int s = 0; s < 2; ++s)
#pragma unroll
    for (int n = 0; n < 2; ++n) bA[s][n] = LDB(0, s, n);

  // KT is even and >= 8 (launcher guarantees). Pair loop exits at u = KT-4.
  int u = 0;
  for (; u + 4 < KT; u += 2) {
    BODY(u,     bA, bB, 4, true, true);
    BODY(u + 1, bB, bA, 4, true, true);
  }
  BODY(u, bA, bB, 4, true,  true);  ++u;   // u = KT-4 (stages KT-1)
  BODY(u, bB, bA, 4, true,  false); ++u;   // u = KT-3
  BODY(u, bA, bB, 0, true,  false); ++u;   // u = KT-2
  BODY(u, bB, bA, 0, false, false);        // u = KT-1
#undef BODY

  // -------- epilogue: C/D layout col=lane&31, row=(reg&3)+8*(reg>>2)+4*(lane>>5)
  const int m0 = rb * 256 + wr * 128;
  const int n0 = cb * 256 + wc * 64;
  const int l31 = lane & 31, lhi = lane >> 5;
#pragma unroll
  for (int n = 0; n < 2; ++n) {
    const int col = n0 + n * 32 + l31;
    const float sc = scale[col];
    const float bi = bias[col];
#pragma unroll
    for (int m = 0; m < 4; ++m) {
      f32x16 v = acc[m][n];
      const int rowb = m0 + m * 32 + 4 * lhi;
#pragma unroll
      for (int q = 0; q < 4; ++q)
#pragma unroll
        for (int r = 0; r < 4; ++r)
          out[(size_t)(rowb + q * 8 + r) * N + col] = v[q * 4 + r] * sc + bi;
    }
  }
}

// ======================================================================
// Fallback (no workspace): 128x128 tile, in-loop dequant, 16x16x32
// ======================================================================
__global__ __launch_bounds__(256) void gemm_fallback(
    const float* __restrict__ x, const int* __restrict__ wq, const int* __restrict__ zp,
    const float* __restrict__ scale, const float* __restrict__ bias,
    float* __restrict__ out, int M, int N, int K) {

  __shared__ unsigned short Alds[128 * 32];
  __shared__ unsigned short Blds[128 * 32];

  const int tid = threadIdx.x;
  const int ntile = N / 128;
  const int m0 = (blockIdx.x / ntile) * 128, n0 = (blockIdx.x % ntile) * 128;
  const int lane = tid & 63;
  const int wave = tid >> 6;
  const int wr = wave >> 1, wc = wave & 1;
  const int lr = lane & 15, lhi = lane >> 4;
  f32x4 acc[4][4] = {};
  const int ar = tid >> 3, ac4 = tid & 7;

  for (int k0 = 0; k0 < K; k0 += 32) {
#pragma unroll
    for (int p = 0; p < 4; ++p) {
      int r = p * 32 + ar;
      i32x4 w = *(const i32x4*)(wq + (size_t)(n0 + r) * K + k0 + ac4 * 4);
      int z = zp[n0 + r];
      u16x4 h;
      h[0] = f2bf((float)(w[0] - z)); h[1] = f2bf((float)(w[1] - z));
      h[2] = f2bf((float)(w[2] - z)); h[3] = f2bf((float)(w[3] - z));
      *(u16x4*)&Blds[r * 32 + ac4 * 4] = h;
    }
#pragma unroll
    for (int p = 0; p < 4; ++p) {
      int r = p * 32 + ar;
      f32x4 v = *(const f32x4*)(x + (size_t)(m0 + r) * K + k0 + ac4 * 4);
      u16x4 h;
      h[0] = f2bf(v[0]); h[1] = f2bf(v[1]); h[2] = f2bf(v[2]); h[3] = f2bf(v[3]);
      *(u16x4*)&Alds[r * 32 + ac4 * 4] = h;
    }
    __syncthreads();
    u32x4 af[4], bf[4];
#pragma unroll
    for (int i = 0; i < 4; ++i) {
      af[i] = *(const u32x4*)&Alds[(wr * 64 + i * 16 + lr) * 32 + lhi * 8];
      bf[i] = *(const u32x4*)&Blds[(wc * 64 + i * 16 + lr) * 32 + lhi * 8];
    }
#pragma unroll
    for (int i = 0; i < 4; ++i)
#pragma unroll
      for (int j = 0; j < 4; ++j)
        mfma16x16x32bf16(acc[i][j], af[i], bf[j]);
    __syncthreads();
  }
  const int crow0 = m0 + wr * 64;
  const int ccol0 = n0 + wc * 64 + lr;
#pragma unroll
  for (int j = 0; j < 4; ++j) {
    int col = ccol0 + j * 16;
    float sc = scale[col], bi = bias[col];
#pragma unroll
    for (int i = 0; i < 4; ++i) {
      int row = crow0 + i * 16 + lhi * 4;
      f32x4 v = acc[i][j];
#pragma unroll
      for (int r = 0; r < 4; ++r)
        out[(size_t)(row + r) * N + col] = v[r] * sc + bi;
    }
  }
}

extern "C" void kernel_launch(void* const* d_in, const int* in_sizes, int n_in,
                              void* d_out, int out_size, void* d_ws, size_t ws_size,
                              hipStream_t stream) {
  const float* x     = (const float*)d_in[0];
  const int*   wq    = (const int*)d_in[1];
  const float* scale = (const float*)d_in[2];
  const int*   zp    = (const int*)d_in[3];
  const float* bias  = (const float*)d_in[4];
  float* out = (float*)d_out;

  const int DOUT = in_sizes[4];             // 4096
  const int DIN  = in_sizes[1] / DOUT;      // 4096
  const int M    = in_sizes[0] / DIN;       // 8192

  const size_t needX = (size_t)M * DIN * 2;
  const size_t needW = (size_t)DOUT * DIN * 2;

  const int nwg  = (M / 256) * (DOUT / 256);
  const int KT64 = DIN / 64;
  const int KT32 = DIN / 32;
  const bool shapes_ok = (M % 256 == 0) && (DOUT % 256 == 0) && (DIN % 64 == 0) &&
                         (nwg % 8 == 0) && (KT32 >= 8) && (KT32 % 2 == 0);

  if (shapes_ok && ws_size >= needX + needW) {
    unsigned short* xb = (unsigned short*)d_ws;
    unsigned short* wb = (unsigned short*)((char*)d_ws + needX);
    prep_x<<<(M / 256) * KT64, 256, 0, stream>>>(x, xb, DIN, KT64);
    prep_w<<<(DOUT / 256) * KT64, 256, 0, stream>>>(wq, zp, wb, DIN, KT64);
    gemm_ring<<<nwg, 512, 0, stream>>>(xb, wb, scale, bias, out, DOUT, KT32);
  } else {
    dim3 grid((M / 128) * (DOUT / 128));
    gemm_fallback<<<grid, 256, 0, stream>>>(x, wq, zp, scale, bias, out, M, DOUT, DIN);
  }
}